// Round 8
// baseline (140.698 us; speedup 1.0000x reference)
//
#include <hip/hip_runtime.h>
#include <hip/hip_bf16.h>

typedef __attribute__((ext_vector_type(8))) short s16x8;
typedef __attribute__((ext_vector_type(4))) float f32x4;
typedef unsigned short u16;
typedef unsigned int u32;

#define NB 16
#define NK 256
#define APP 768
#define DKK 96
#define NR 8
#define QSCALE 0.10206207261596575f   // 1/sqrt(96), folded into Q at projection

__device__ __forceinline__ u16 f2bf(float f) {
  union { float f; unsigned int u; } v; v.f = f;
  unsigned int x = v.u;
  x += 0x7fffu + ((x >> 16) & 1u);
  return (u16)(x >> 16);
}
__device__ __forceinline__ float bf2f(u16 h) {
  union { unsigned int u; float f; } v; v.u = ((unsigned int)h) << 16;
  return v.f;
}
__device__ __forceinline__ u32 cvtpk(float lo, float hi) {
  u32 r;
  asm("v_cvt_pk_bf16_f32 %0, %1, %2" : "=v"(r) : "v"(lo), "v"(hi));
  return r;
}
__device__ __forceinline__ float bflo(u32 pk) {   // float of low bf16
  union { u32 u; float f; } v; v.u = pk << 16; return v.f;
}
__device__ __forceinline__ float bfhi(u32 pk) {   // float of high bf16
  union { u32 u; float f; } v; v.u = pk & 0xffff0000u; return v.f;
}
__device__ __forceinline__ void gload_lds16(const void* g, void* l) {
  __builtin_amdgcn_global_load_lds(
      (const __attribute__((address_space(1))) unsigned int*)g,
      (__attribute__((address_space(3))) unsigned int*)l, 16, 0, 0);
}

// ---------------------------------------------------------------------------
// Kernel 0: convert f_a and the 3 projection weights to bf16.
// ---------------------------------------------------------------------------
__global__ __launch_bounds__(256) void conv_kernel(
    const float* __restrict__ fa,
    const float* __restrict__ WKw, const float* __restrict__ WQw,
    const float* __restrict__ WVw,
    u16* __restrict__ fab, u16* __restrict__ Wb)
{
  const int idx = blockIdx.x * 256 + threadIdx.x;
  const int faCh = NB * NK * APP / 8;      // 393216
  const int wCh  = NR * DKK * APP / 8;     // 73728 per weight array
  const float* src; u16* dst;
  if (idx < faCh) {
    src = fa + (size_t)idx * 8;
    dst = fab + (size_t)idx * 8;
  } else {
    int o = idx - faCh;
    int a = o / wCh;
    int oo = o - a * wCh;
    const float* wsrc = a == 0 ? WKw : (a == 1 ? WQw : WVw);
    src = wsrc + (size_t)oo * 8;
    dst = Wb + (size_t)a * (NR * DKK * APP) + (size_t)oo * 8;
  }
  float4 v0 = *(const float4*)src;
  float4 v1 = *(const float4*)(src + 4);
  s16x8 ov = {(short)f2bf(v0.x),(short)f2bf(v0.y),(short)f2bf(v0.z),(short)f2bf(v0.w),
              (short)f2bf(v1.x),(short)f2bf(v1.y),(short)f2bf(v1.z),(short)f2bf(v1.w)};
  *(s16x8*)dst = ov;
}

// ---------------------------------------------------------------------------
// Kernel 1 (FUSED proj + wg): one grid, proj block every 15th bid
// (576 proj : 8192 wg) so every CU co-hosts the MFMA-bound proj GEMM and the
// HBM-streaming wg pass.
//
// proj: C[m,c]=fab[m,:].Wb[c,:]+bias, 128x128 tile, BK=64, gload_lds w=16,
//   both-sides XOR swizzle; frag-major outputs (LDS 32 KB).
// wg (LDS-FREE): lane (c,g) loads pos rows directly in MFMA A-frag layout
//   (all 12 float4 issued upfront for MLP), converts to hi/lo bf16 in
//   registers, 3-term MFMA; merged packed uint2 stores (all 64 lanes).
// ---------------------------------------------------------------------------
#define PROJ_BLKS 576
#define WG_BLKS 8192

__global__ __launch_bounds__(256) void fused_kernel(
    const u16* __restrict__ fab, const u16* __restrict__ Wb,
    const float* __restrict__ WKb, const float* __restrict__ WQb,
    const float* __restrict__ WVb,
    u16* __restrict__ wkF, u16* __restrict__ wqF, u16* __restrict__ wvF,
    const float* __restrict__ pos,
    const float* __restrict__ WGw, const float* __restrict__ WGb,
    u16* __restrict__ lb2)
{
  __shared__ u16 SH[16384];              // 32 KB, proj path only
  const int t = threadIdx.x;
  const int lane = t & 63, w = t >> 6;
  const int c = lane & 15, g = lane >> 4;
  const int bid = blockIdx.x;
  const int q = bid / 15, rph = bid - q * 15;

  if (rph == 0 && q < PROJ_BLKS) {
    // ----------------------- proj path -----------------------
    u16* As = SH;                        // 8192 elems
    u16* Bs = SH + 8192;
    const int pb = q;
    const int wr = w >> 1, wc = w & 1;
    const int m0 = (pb & 31) * 128;
    const int ct = pb >> 5;              // 0..17
    const int c0 = ct * 128;

    f32x4 acc[4][4] = {};

    for (int k0 = 0; k0 < APP; k0 += 64) {
      __syncthreads();
      #pragma unroll
      for (int i = 0; i < 4; ++i) {
        int n = t + i * 256;             // chunk id, 0..1023
        int row = n >> 3, cg = n & 7;
        int scg = cg ^ (row & 7);        // pre-swizzled global col-group
        gload_lds16(fab + (size_t)(m0 + row) * APP + k0 + scg * 8, As + n * 8);
        gload_lds16(Wb  + (size_t)(c0 + row) * APP + k0 + scg * 8, Bs + n * 8);
      }
      __syncthreads();
      #pragma unroll
      for (int kc = 0; kc < 2; ++kc) {
        s16x8 af[4], bfr[4];
        #pragma unroll
        for (int i = 0; i < 4; ++i) {
          int arow = wr * 64 + i * 16 + c;
          af[i]  = *(const s16x8*)(As + (((arow << 3) | ((kc * 4 + g) ^ (arow & 7))) << 3));
          int brow = wc * 64 + i * 16 + c;
          bfr[i] = *(const s16x8*)(Bs + (((brow << 3) | ((kc * 4 + g) ^ (brow & 7))) << 3));
        }
        #pragma unroll
        for (int mi = 0; mi < 4; ++mi)
          #pragma unroll
          for (int ni = 0; ni < 4; ++ni)
            acc[mi][ni] = __builtin_amdgcn_mfma_f32_16x16x32_bf16(af[mi], bfr[ni], acc[mi][ni], 0, 0, 0);
      }
    }

    const int arr = ct / 6;              // 0=K 1=Q 2=V (tiles never straddle)
    const int cw0 = c0 - arr * APP;
    const float* bp = arr == 0 ? WKb : (arr == 1 ? WQb : WVb);

    #pragma unroll
    for (int mi = 0; mi < 4; ++mi)
      #pragma unroll
      for (int ni = 0; ni < 4; ++ni) {
        int clw = cw0 + wc * 64 + ni * 16 + c;    // 0..767
        float bias = bp[clw];
        int rr = clw / DKK, kk = clw - rr * DKK;  // r, k-within-head
        int mb = m0 + wr * 64 + mi * 16 + g * 4;  // 4 consecutive m
        int bi = mb >> 8, tt = mb & 255;
        size_t hb = (size_t)rr * NB + bi;
        if (arr == 2) {
          ushort4 pk4;
          pk4.x = f2bf(acc[mi][ni][0] + bias);
          pk4.y = f2bf(acc[mi][ni][1] + bias);
          pk4.z = f2bf(acc[mi][ni][2] + bias);
          pk4.w = f2bf(acc[mi][ni][3] + bias);
          *(ushort4*)&wvF[((hb * 32 + (tt >> 3)) * DKK + kk) * 8 + (tt & 7)] = pk4;
        } else {
          u16* op = arr == 0 ? wkF : wqF;
          size_t base = ((hb * 12 + (kk >> 3)) * NK) * 8 + (size_t)(kk & 7);
          #pragma unroll
          for (int e = 0; e < 4; ++e) {
            float val = acc[mi][ni][e] + bias;
            if (arr == 1) val *= QSCALE;
            op[base + (size_t)(tt + e) * 8] = f2bf(val);
          }
        }
      }
  } else {
    // ----------------------- wg path (LDS-free) -----------------------
    const int nbefore = (q >= PROJ_BLKS) ? PROJ_BLKS : (q + (rph > 0 ? 1 : 0));
    const int wgid = bid - nbefore;      // 0..8191
    const size_t row0 = (size_t)wgid * 128;

    // B-frags (hi/lo): lane (c,g) holds W[c&7][kc*32+g*8 .. +8]
    s16x8 bwh[3], bwl[3];
    #pragma unroll
    for (int kc = 0; kc < 3; ++kc) {
      const float* wp = WGw + (c & 7) * DKK + kc * 32 + g * 8;
      s16x8 hv, lv;
      #pragma unroll
      for (int j = 0; j < 4; ++j) {
        float x0 = wp[2 * j], x1 = wp[2 * j + 1];
        u32 h = cvtpk(x0, x1);
        u32 l = cvtpk(x0 - bflo(h), x1 - bfhi(h));
        hv[2 * j] = (short)(h & 0xffff); hv[2 * j + 1] = (short)(h >> 16);
        lv[2 * j] = (short)(l & 0xffff); lv[2 * j + 1] = (short)(l >> 16);
      }
      bwh[kc] = hv; bwl[kc] = lv;
    }
    const float bias = WGb[c & 7];

    // A-frag direct loads: lane (c,g), group gi -> row row0+w*32+gi*16+c,
    // cols kc*32+g*8 .. +8.  All 12 float4 issued upfront (MLP).
    float4 ra[2][3][2];
    #pragma unroll
    for (int gi = 0; gi < 2; ++gi) {
      const float* prow = pos + (row0 + w * 32 + gi * 16 + c) * DKK + g * 8;
      #pragma unroll
      for (int kc = 0; kc < 3; ++kc) {
        ra[gi][kc][0] = *(const float4*)(prow + kc * 32);
        ra[gi][kc][1] = *(const float4*)(prow + kc * 32 + 4);
      }
    }

    f32x4 acc0 = {0.f, 0.f, 0.f, 0.f}, acc1 = {0.f, 0.f, 0.f, 0.f};
    #pragma unroll
    for (int gi = 0; gi < 2; ++gi) {
      f32x4 acc = {0.f, 0.f, 0.f, 0.f};
      #pragma unroll
      for (int kc = 0; kc < 3; ++kc) {
        float4 a = ra[gi][kc][0];
        float4 b = ra[gi][kc][1];
        u32 h0 = cvtpk(a.x, a.y), h1 = cvtpk(a.z, a.w);
        u32 h2 = cvtpk(b.x, b.y), h3 = cvtpk(b.z, b.w);
        u32 l0 = cvtpk(a.x - bflo(h0), a.y - bfhi(h0));
        u32 l1 = cvtpk(a.z - bflo(h1), a.w - bfhi(h1));
        u32 l2 = cvtpk(b.x - bflo(h2), b.y - bfhi(h2));
        u32 l3 = cvtpk(b.z - bflo(h3), b.w - bfhi(h3));
        uint4 hv = {h0, h1, h2, h3}, lv = {l0, l1, l2, l3};
        s16x8 ah = *(s16x8*)&hv, al = *(s16x8*)&lv;
        acc = __builtin_amdgcn_mfma_f32_16x16x32_bf16(ah, bwh[kc], acc, 0, 0, 0);
        acc = __builtin_amdgcn_mfma_f32_16x16x32_bf16(ah, bwl[kc], acc, 0, 0, 0);
        acc = __builtin_amdgcn_mfma_f32_16x16x32_bf16(al, bwh[kc], acc, 0, 0, 0);
      }
      if (gi == 0) acc0 = acc; else acc1 = acc;
    }

    // merged store: B-cols 8..15 duplicate 0..7, so lanes c<8 hold group-0
    // results and c>=8 hold identical group-1 results -> all 64 lanes store.
    {
      int gi = c >> 3;
      f32x4 acc = gi ? acc1 : acc0;
      size_t base = (size_t)(c & 7) * (NB * NK * NK) + row0 + w * 32 + gi * 16 + g * 4;
      float v0 = __logf(fmaxf(acc[0] + bias, 1e-6f));
      float v1 = __logf(fmaxf(acc[1] + bias, 1e-6f));
      float v2 = __logf(fmaxf(acc[2] + bias, 1e-6f));
      float v3 = __logf(fmaxf(acc[3] + bias, 1e-6f));
      uint2 pk;
      pk.x = cvtpk(v0, v1);
      pk.y = cvtpk(v2, v3);
      *(uint2*)(lb2 + base) = pk;        // 8B packed store
    }
  }
}

// ---------------------------------------------------------------------------
// Kernel 2: attention.  512 blocks (4 nb x 16 b x 8 r), 4 waves each, wave owns
// 16 query rows (n).  All K/Q/V frag loads are dense 1-KB instrs (frag-major
// layouts); bias preloaded; softmax in-reg; PV via tiny per-wave LDS P chunks.
// ---------------------------------------------------------------------------
__global__ __launch_bounds__(256) void attn_kernel(
    const u16* __restrict__ wkF, const u16* __restrict__ wqF,
    const u16* __restrict__ wvF, const u16* __restrict__ lb2,
    const float* __restrict__ fa, float* __restrict__ out)
{
  __shared__ u16 Ps[4][16][40];   // per-wave P chunk [16 n][32 m]
  const int t = threadIdx.x;
  const int w = t >> 6, lane = t & 63;
  const int c = lane & 15, g = lane >> 4;
  const int b = blockIdx.y, r = blockIdx.z;
  const int nb = blockIdx.x * 64 + w * 16;

  const size_t hb = (size_t)r * NB + b;
  const u16* Qb = wqF + hb * (12 * NK * 8);
  const u16* Kb = wkF + hb * (12 * NK * 8);
  const u16* Vb = wvF + hb * (32 * DKK * 8);
  const u16* Br = lb2 + hb * NK * NK + (size_t)c * NK + nb + g * 4;

  s16x8 qf[3];
  #pragma unroll
  for (int kc = 0; kc < 3; ++kc)
    qf[kc] = *(const s16x8*)(Qb + ((kc * 4 + g) * NK + nb + c) * 8);

  // preload all 16 bias quads
  ushort4 bbr[16];
  #pragma unroll
  for (int mt = 0; mt < 16; ++mt)
    bbr[mt] = *(const ushort4*)(Br + (size_t)mt * 16 * NK);

  // S[n = nb+g*4+e][m = mt*16+c]
  f32x4 S[16];
  #pragma unroll
  for (int mt = 0; mt < 16; ++mt) {
    f32x4 sa = {bf2f(bbr[mt].x), bf2f(bbr[mt].y), bf2f(bbr[mt].z), bf2f(bbr[mt].w)};
    #pragma unroll
    for (int kc = 0; kc < 3; ++kc) {
      s16x8 kf = *(const s16x8*)(Kb + ((kc * 4 + g) * NK + mt * 16 + c) * 8);
      sa = __builtin_amdgcn_mfma_f32_16x16x32_bf16(qf[kc], kf, sa, 0, 0, 0);
    }
    S[mt] = sa;
  }

  // softmax over m: 16 in-lane + shfl_xor over the 16 c-lanes
  float rinv[4];
  #pragma unroll
  for (int e = 0; e < 4; ++e) {
    float mx = S[0][e];
    #pragma unroll
    for (int mt = 1; mt < 16; ++mt) mx = fmaxf(mx, S[mt][e]);
    mx = fmaxf(mx, __shfl_xor(mx, 1));
    mx = fmaxf(mx, __shfl_xor(mx, 2));
    mx = fmaxf(mx, __shfl_xor(mx, 4));
    mx = fmaxf(mx, __shfl_xor(mx, 8));
    float sm = 0.f;
    #pragma unroll
    for (int mt = 0; mt < 16; ++mt) {
      float p = __expf(S[mt][e] - mx);
      S[mt][e] = p;
      sm += p;
    }
    sm += __shfl_xor(sm, 1);
    sm += __shfl_xor(sm, 2);
    sm += __shfl_xor(sm, 4);
    sm += __shfl_xor(sm, 8);
    rinv[e] = 1.f / sm;
  }

  // PV in 8 chunks of 32 m
  f32x4 o[6];
  #pragma unroll
  for (int ki = 0; ki < 6; ++ki) o[ki] = (f32x4){0.f, 0.f, 0.f, 0.f};

  #pragma unroll
  for (int mc = 0; mc < 8; ++mc) {
    #pragma unroll
    for (int e = 0; e < 4; ++e) {
      Ps[w][g * 4 + e][c]      = f2bf(S[2 * mc][e]);
      Ps[w][g * 4 + e][16 + c] = f2bf(S[2 * mc + 1][e]);
    }
    s16x8 pa = *(const s16x8*)&Ps[w][c][g * 8];
    #pragma unroll
    for (int ki = 0; ki < 6; ++ki) {
      s16x8 vf = *(const s16x8*)(Vb + ((mc * 4 + g) * DKK + ki * 16 + c) * 8);
      o[ki] = __builtin_amdgcn_mfma_f32_16x16x32_bf16(pa, vf, o[ki], 0, 0, 0);
    }
  }

  // epilogue: normalize, residual, fp32 store
  #pragma unroll
  for (int ki = 0; ki < 6; ++ki)
    #pragma unroll
    for (int e = 0; e < 4; ++e) {
      int n = nb + g * 4 + e;
      size_t adr = ((size_t)b * NK + n) * (NR * DKK) + r * DKK + ki * 16 + c;
      out[adr] = o[ki][e] * rinv[e] + fa[adr];
    }
}

extern "C" void kernel_launch(void* const* d_in, const int* in_sizes, int n_in,
                              void* d_out, int out_size, void* d_ws, size_t ws_size,
                              hipStream_t stream) {
  (void)in_sizes; (void)n_in; (void)out_size; (void)ws_size;
  const float* fa  = (const float*)d_in[0];
  const float* pos = (const float*)d_in[1];
  const float* WGw = (const float*)d_in[2];
  const float* WGb = (const float*)d_in[3];
  const float* WKw = (const float*)d_in[4];
  const float* WKb = (const float*)d_in[5];
  const float* WQw = (const float*)d_in[6];
  const float* WQb = (const float*)d_in[7];
  const float* WVw = (const float*)d_in[8];
  const float* WVb = (const float*)d_in[9];
  float* outp = (float*)d_out;

  const size_t faN = (size_t)NB * NK * APP;       // 3,145,728
  const size_t wN  = (size_t)3 * NR * DKK * APP;  // 1,769,472
  const size_t kqv = (size_t)NR * NB * NK * DKK;  // 3,145,728 (all 3 layouts)
  u16* fab = (u16*)d_ws;
  u16* Wb  = fab + faN;
  u16* wkF = Wb + wN;
  u16* wqF = wkF + kqv;
  u16* wvF = wqF + kqv;
  u16* lb2 = wvF + kqv;

  hipLaunchKernelGGL(conv_kernel, dim3(2400), dim3(256), 0, stream,
                     fa, WKw, WQw, WVw, fab, Wb);
  hipLaunchKernelGGL(fused_kernel, dim3(PROJ_BLKS + WG_BLKS), dim3(256), 0, stream,
                     fab, Wb, WKb, WQb, WVb, wkF, wqF, wvF, pos, WGw, WGb, lb2);
  hipLaunchKernelGGL(attn_kernel, dim3(4, NB, NR), dim3(256), 0, stream,
                     wkF, wqF, wvF, lb2, fa, outp);
}